// Round 9
// baseline (347.108 us; speedup 1.0000x reference)
//
#include <hip/hip_runtime.h>

// AGCRNCell on gfx950.  B=32, N=2048, C=66, CHEB_K=3, F=2112 (= 33*64, exact).
// R9: 64x64 GEMM tiles / 2-wave blocks. R8 insight: LDS allowed 3 blocks/CU but the
//     528-block grid only delivered 2.06 -- co-residency was grid-limited, not
//     LDS-limited. 64x64 tile keeps the per-wave structure identical (64x32 wave
//     tile, 4x2 frags 16x16x32, BK=64, XOR-granule swizzle) but grid = 1056 blocks
//     = 4.1 blocks/CU (dbuf 32 KB, capacity 5), 4 independent barrier domains/CU.
//     Pipeline: stage next buf -> s_waitcnt vmcnt(8) (own cur loads) -> raw
//     s_barrier -> compute -> raw s_barrier. Kept: fused G epilogues (sections
//     0/72/144), build_t2 -> G sec0, no transpose_g / T2.

typedef __bf16 bf16x8 __attribute__((ext_vector_type(8)));
typedef __bf16 bf16x4 __attribute__((ext_vector_type(4)));
typedef float  f32x4  __attribute__((ext_vector_type(4)));

#define GLB(p) ((__attribute__((address_space(1))) void*)(void*)(p))
#define LDS(p) ((__attribute__((address_space(3))) void*)(p))

// ---------------- supports: S[n][m] = softmax_m(relu(E[n]·E[m])) ----------------
__global__ void supports_kernel(const float* __restrict__ E, __bf16* __restrict__ S) {
    const int n = blockIdx.x;
    const int t = threadIdx.x;            // 256
    const int l = t & 63, w = t >> 6;
    float en[10];
#pragma unroll
    for (int i = 0; i < 10; ++i) en[i] = E[n * 10 + i];
    float vals[8];
    float mx = 0.f;
#pragma unroll
    for (int q = 0; q < 8; ++q) {
        const int m = q * 256 + t;
        const float* em = E + (size_t)m * 10;
        float d = 0.f;
#pragma unroll
        for (int i = 0; i < 10; ++i) d += en[i] * em[i];
        d = fmaxf(d, 0.f);
        vals[q] = d;
        mx = fmaxf(mx, d);
    }
#pragma unroll
    for (int off = 32; off; off >>= 1) mx = fmaxf(mx, __shfl_xor(mx, off));
    __shared__ float sm[4], ss[4];
    if (l == 0) sm[w] = mx;
    __syncthreads();
    mx = fmaxf(fmaxf(sm[0], sm[1]), fmaxf(sm[2], sm[3]));
    float sum = 0.f;
#pragma unroll
    for (int q = 0; q < 8; ++q) { vals[q] = __expf(vals[q] - mx); sum += vals[q]; }
#pragma unroll
    for (int off = 32; off; off >>= 1) sum += __shfl_xor(sum, off);
    if (l == 0) ss[w] = sum;
    __syncthreads();
    sum = ss[0] + ss[1] + ss[2] + ss[3];
    const float inv = 1.f / sum;
#pragma unroll
    for (int q = 0; q < 8; ++q) S[(size_t)n * 2048 + q * 256 + t] = (__bf16)(vals[q] * inv);
}

// ------- build T0 (T-layout [f=b*66+c][n]) + G section 0 (k in [0,72)) -------
__global__ __launch_bounds__(256, 2)
void build_t2(const float* __restrict__ x, const float* __restrict__ st,
              const __bf16* __restrict__ zr, __bf16* __restrict__ T,
              __bf16* __restrict__ G) {
    __shared__ float Ls[66 * 129];       // 34 KB
    const int b  = blockIdx.x >> 4;
    const int n0 = (blockIdx.x & 15) << 7;
    const int t = threadIdx.x;
    const size_t mb = (size_t)b * 2048 + n0;
    if (t < 128) {
        const float2 v = *(const float2*)&x[(mb + t) * 2];
        Ls[t] = v.x;
        Ls[129 + t] = v.y;
    }
#pragma unroll
    for (int r = 0; r < 8; ++r) {        // 128 rows x 16 col-quads
        const int task = r * 256 + t;
        const int q = task & 15, n = task >> 4;
        f32x4 v = *(const f32x4*)&st[(mb + n) * 64 + q * 4];
        if (zr) {
            const bf16x4 z = *(const bf16x4*)&zr[(mb + n) * 128 + q * 4];
#pragma unroll
            for (int j = 0; j < 4; ++j) v[j] *= (float)z[j];
        }
        const int base = (2 + q * 4) * 129 + n;
#pragma unroll
        for (int j = 0; j < 4; ++j) Ls[base + j * 129] = v[j];
    }
    __syncthreads();
    // T-layout store: coalesced columns
#pragma unroll
    for (int r = 0; r < 5; ++r) {        // 66 c x 16 segs = 1056 tasks
        const int task = r * 256 + t;
        if (task < 1056) {
            const int c = task >> 4, seg = task & 15;
            const float* src = &Ls[c * 129 + seg * 8];
            bf16x8 o;
#pragma unroll
            for (int j = 0; j < 8; ++j) o[j] = (__bf16)src[j];
            *(bf16x8*)&T[(size_t)(b * 66 + c) * 2048 + n0 + seg * 8] = o;
        }
    }
    // G section 0: row (b, n0+n), k = cc in [0,66), octets 0..8 (cc>=66 -> 0)
    {
        const int n = t & 127, half = t >> 7;
        const size_t grow = ((size_t)(b * 2048 + n0 + n)) * 256;
        for (int oct = half * 5; oct < (half ? 9 : 5); ++oct) {
            bf16x8 o8;
#pragma unroll
            for (int j = 0; j < 8; ++j) {
                const int cc = oct * 8 + j;
                o8[j] = (cc < 66) ? (__bf16)Ls[cc * 129 + n] : (__bf16)0.f;
            }
            *(bf16x8*)&G[grow + oct * 8] = o8;
        }
    }
}

// ---- build W^T with section-padded k: WT[o][k], k = 72*jj + cc, cc<66 real ----
__global__ void build_wt(const float* __restrict__ W, __bf16* __restrict__ WT, int Nout) {
    const int id = blockIdx.x * 256 + threadIdx.x;   // 128*256
    const int o = id >> 8, k = id & 255;
    const int jj = (k >= 144) ? 2 : (k >= 72 ? 1 : 0);
    const int cc = k - 72 * jj;
    const bool ok = (o < Nout) && (cc < 66) && (k < 216);
    WT[id] = ok ? (__bf16)W[(size_t)(66 * jj + cc) * Nout + o] : (__bf16)0.f;
}

// ---------------- pipelined GEMM: out[M][C] = A[M][K] @ Bt[C][K]^T ----------------
// 128 thr = 2 waves (c-split), tile 64m x 64c, wave-tile 64x32 (4x2 frags), BK=64.
// Double-buffered LDS (32 KB -> 5 blocks/CU capacity); per iter: stage next buf
// (8 global_load_lds/thread) -> s_waitcnt vmcnt(8) -> raw s_barrier -> compute ->
// raw s_barrier. XOR-granule swizzle (slot = g ^ (row&7)): conflict-free b128.
// swz=1: mt = id&31, ct = id>>5 (pins each A strip to one XCD's L2).
// epi: 0 outT[c][m]=bf16(acc), + G sec (gsec=72)
//      1 G sec only (gsec=144), val = 2*acc - subT[c][m]
//      2 zrO[m*128+c] = bf16(sigmoid(acc+bias[c]))
//      3 outF[m*64+c] = r*state+(1-r)*tanh(acc+bias[c]), r=zrI[m*128+64+c]
__global__ __launch_bounds__(128, 2)
void gemm_pipe(const __bf16* __restrict__ A, int lda,
               const __bf16* __restrict__ Bt, int ldb,
               int K, int epi, int swz,
               __bf16* __restrict__ outT, const __bf16* __restrict__ subT,
               float* __restrict__ outF, const float* __restrict__ bias,
               __bf16* __restrict__ zrO, const __bf16* __restrict__ zrI,
               const float* __restrict__ state,
               __bf16* __restrict__ Gout, int gsec) {
    __shared__ __align__(16) __bf16 As[2][64 * 64];    // 16 KB
    __shared__ __align__(16) __bf16 Bs[2][64 * 64];    // 16 KB
    int mt, ct;
    if (swz) { mt = blockIdx.x & 31; ct = blockIdx.x >> 5; }
    else     { mt = blockIdx.x;      ct = blockIdx.y; }
    const int m0 = mt * 64, c0 = ct * 64;
    const int t = threadIdx.x;           // 128
    const int l = t & 63, w = t >> 6;    // 2 waves: w = c-half
    const int lm = l & 15, kq = l >> 4, lm7 = lm & 7;
    const int sr = t >> 3;               // staging row-within-16 (0..15)
    const int gsw = (t & 7) ^ (sr & 7);  // swizzled source granule

    f32x4 acc[4][2];
#pragma unroll
    for (int i = 0; i < 4; ++i)
#pragma unroll
        for (int j = 0; j < 2; ++j) acc[i][j] = (f32x4)0.f;

    const __bf16* Asrc = A  + (size_t)(m0 + sr) * lda + gsw * 8;
    const __bf16* Bsrc = Bt + (size_t)(c0 + sr) * ldb + gsw * 8;
    const int dst = t * 8;               // lane-linear LDS dest (elements)

    auto stage = [&](int buf, int k0) {
#pragma unroll
        for (int q = 0; q < 4; ++q)
            __builtin_amdgcn_global_load_lds(GLB(Asrc + (size_t)q * 16 * lda + k0),
                                             LDS(&As[buf][q * 1024 + dst]), 16, 0, 0);
#pragma unroll
        for (int q = 0; q < 4; ++q)
            __builtin_amdgcn_global_load_lds(GLB(Bsrc + (size_t)q * 16 * ldb + k0),
                                             LDS(&Bs[buf][q * 1024 + dst]), 16, 0, 0);
    };
    auto compute = [&](int buf) {
        const __bf16* Ab = &As[buf][0];
        const __bf16* Bb = &Bs[buf][0];
#pragma unroll
        for (int ks = 0; ks < 2; ++ks) {
            const int ga = (((ks << 2) | kq) ^ lm7) << 3;
            bf16x8 af[4], bfr[2];
#pragma unroll
            for (int i = 0; i < 4; ++i)
                af[i] = *(const bf16x8*)&Ab[(i * 16 + lm) * 64 + ga];
#pragma unroll
            for (int j = 0; j < 2; ++j)
                bfr[j] = *(const bf16x8*)&Bb[(w * 32 + j * 16 + lm) * 64 + ga];
#pragma unroll
            for (int i = 0; i < 4; ++i)
#pragma unroll
                for (int j = 0; j < 2; ++j)
                    acc[i][j] = __builtin_amdgcn_mfma_f32_16x16x32_bf16(af[i], bfr[j], acc[i][j], 0, 0, 0);
        }
    };

    stage(0, 0);
    const int iters = K >> 6;            // even (32 big / 4 W)
    for (int i = 0; i + 2 <= iters; i += 2) {
        stage(1, (i + 1) << 6);
        __builtin_amdgcn_sched_barrier(0);
        __builtin_amdgcn_s_waitcnt(0x0F78);      // vmcnt(8): own buf0 loads done
        __builtin_amdgcn_s_barrier();
        __builtin_amdgcn_sched_barrier(0);
        compute(0);
        __builtin_amdgcn_sched_barrier(0);
        __builtin_amdgcn_s_barrier();            // buf0 free for restage
        __builtin_amdgcn_sched_barrier(0);
        if (i + 2 < iters) {
            stage(0, (i + 2) << 6);
            __builtin_amdgcn_sched_barrier(0);
            __builtin_amdgcn_s_waitcnt(0x0F78);  // vmcnt(8): own buf1 loads done
        } else {
            __builtin_amdgcn_s_waitcnt(0x0F70);  // vmcnt(0)
        }
        __builtin_amdgcn_s_barrier();
        __builtin_amdgcn_sched_barrier(0);
        compute(1);
        __builtin_amdgcn_sched_barrier(0);
        if (i + 4 <= iters) {
            __builtin_amdgcn_s_barrier();        // buf1 free for restage
            __builtin_amdgcn_sched_barrier(0);
        }
    }

    // epilogue: C row = m (quad*4+reg), col = lane&15  [verified m89 layout]
    const int rb0 = m0 + kq * 4;
    const int cb0 = c0 + w * 32 + lm;
#pragma unroll
    for (int i = 0; i < 4; ++i) {
        const int rbase = rb0 + i * 16;
#pragma unroll
        for (int j = 0; j < 2; ++j) {
            const int c = cb0 + j * 16;
            f32x4 v = acc[i][j];
            if (epi <= 1) {
                bf16x4 pk;
                if (epi == 0) {
#pragma unroll
                    for (int r = 0; r < 4; ++r) pk[r] = (__bf16)v[r];
                    *(bf16x4*)&outT[(size_t)c * 2048 + rbase] = pk;
                } else {
                    bf16x4 s = *(const bf16x4*)&subT[(size_t)c * 2048 + rbase];
#pragma unroll
                    for (int r = 0; r < 4; ++r) pk[r] = (__bf16)(2.f * v[r] - (float)s[r]);
                }
                // G scatter: row (b, n=rbase+r), k = gsec + cc, b = c/66
                const int b = c / 66, cc = c - b * 66;
                const size_t gb = ((size_t)(b * 2048 + rbase)) * 256 + gsec + cc;
#pragma unroll
                for (int r = 0; r < 4; ++r) Gout[gb + (size_t)r * 256] = pk[r];
            } else if (epi == 2) {
                const float bb = bias[c];
#pragma unroll
                for (int r = 0; r < 4; ++r) {
                    float xx = fminf(fmaxf(v[r] + bb, -30.f), 30.f);
                    zrO[(size_t)(rbase + r) * 128 + c] = (__bf16)(1.f / (1.f + __expf(-xx)));
                }
            } else {
                const float bb = bias[c];
#pragma unroll
                for (int r = 0; r < 4; ++r) {
                    const int m = rbase + r;
                    float xx = fminf(fmaxf(v[r] + bb, -15.f), 15.f);
                    float e = __expf(2.f * xx);
                    float hc = (e - 1.f) / (e + 1.f);
                    float rr = (float)zrI[(size_t)m * 128 + 64 + c];
                    float s = state[(size_t)m * 64 + c];
                    outF[(size_t)m * 64 + c] = rr * s + (1.f - rr) * hc;
                }
            }
        }
    }
}

extern "C" void kernel_launch(void* const* d_in, const int* in_sizes, int n_in,
                              void* d_out, int out_size, void* d_ws, size_t ws_size,
                              hipStream_t stream) {
    (void)in_sizes; (void)n_in; (void)out_size; (void)ws_size;
    const float* x  = (const float*)d_in[0];
    const float* st = (const float*)d_in[1];
    const float* E  = (const float*)d_in[2];
    const float* Wg = (const float*)d_in[3];
    const float* bg = (const float*)d_in[4];
    const float* Wu = (const float*)d_in[5];
    const float* bu = (const float*)d_in[6];
    float* out = (float*)d_out;

    char* p = (char*)d_ws;
    __bf16* S   = (__bf16*)p; p += (size_t)2048 * 2048 * 2;   // 8.4 MB
    __bf16* T0  = (__bf16*)p; p += (size_t)2112 * 2048 * 2;   // 8.65 MB
    __bf16* T1  = (__bf16*)p; p += (size_t)2112 * 2048 * 2;
    __bf16* G   = (__bf16*)p; p += (size_t)65536 * 256 * 2;   // 33.6 MB
    __bf16* ZR  = (__bf16*)p; p += (size_t)65536 * 128 * 2;   // 16.8 MB
    __bf16* WTg = (__bf16*)p; p += 128 * 256 * 2;
    __bf16* WTu = (__bf16*)p; p += 128 * 256 * 2;             // ~76 MB

    build_wt<<<128, 256, 0, stream>>>(Wg, WTg, 128);
    build_wt<<<128, 256, 0, stream>>>(Wu, WTu, 64);
    supports_kernel<<<2048, 256, 0, stream>>>(E, S);

    // gate phase
    build_t2<<<512, 256, 0, stream>>>(x, st, nullptr, T0, G);
    gemm_pipe<<<1056, 128, 0, stream>>>(S, 2048, T0, 2048, 2048, 0, 1, T1, nullptr, nullptr, nullptr, nullptr, nullptr, nullptr, G, 72);
    gemm_pipe<<<1056, 128, 0, stream>>>(S, 2048, T1, 2048, 2048, 1, 1, nullptr, T0, nullptr, nullptr, nullptr, nullptr, nullptr, G, 144);
    gemm_pipe<<<dim3(1024, 2), 128, 0, stream>>>(G, 256, WTg, 256, 256, 2, 0, nullptr, nullptr, nullptr, bg, ZR, nullptr, nullptr, nullptr, 0);

    // update phase
    build_t2<<<512, 256, 0, stream>>>(x, st, ZR, T0, G);
    gemm_pipe<<<1056, 128, 0, stream>>>(S, 2048, T0, 2048, 2048, 0, 1, T1, nullptr, nullptr, nullptr, nullptr, nullptr, nullptr, G, 72);
    gemm_pipe<<<1056, 128, 0, stream>>>(S, 2048, T1, 2048, 2048, 1, 1, nullptr, T0, nullptr, nullptr, nullptr, nullptr, nullptr, G, 144);
    gemm_pipe<<<dim3(1024, 1), 128, 0, stream>>>(G, 256, WTu, 256, 256, 3, 0, nullptr, nullptr, out, bu, nullptr, ZR, st, nullptr, 0);
}

// Round 10
// 265.492 us; speedup vs baseline: 1.3074x; 1.3074x over previous
//
#include <hip/hip_runtime.h>

// AGCRNCell on gfx950.  B=32, N=2048, C=66, CHEB_K=3, F=2112 (= 33*64, exact).
// R10: consolidation to the measured optimum. GEMM core = R8 (128m x 64c, 4 waves,
//      48 KB dbuf, vmcnt(6)+raw-barrier, launch_bounds(256,3), XCD swizzle).
//      Structure search closed: R5 1-wave (72us), R7 tri-buffer (61us), R9 64x64
//      2-wave (55us) all regressed vs this core's 38-39us; tile perturbations trade
//      intra-block TLP against residency with no net win at M=2048 / 528 blocks.
//      New in R10: supports + both build_wt fused into one prologue launch.
//      Kept: fused G epilogues (sections 0/72/144), build_t2 -> G sec0, no
//      transpose_g / T2.

typedef __bf16 bf16x8 __attribute__((ext_vector_type(8)));
typedef __bf16 bf16x4 __attribute__((ext_vector_type(4)));
typedef float  f32x4  __attribute__((ext_vector_type(4)));

#define GLB(p) ((__attribute__((address_space(1))) void*)(void*)(p))
#define LDS(p) ((__attribute__((address_space(3))) void*)(p))

// ---- fused prologue ----
// blocks [0,2048):   S[n][m] = softmax_m(relu(E[n]·E[m]))
// blocks [2048,2176): WTg[o][k] (section-padded k: k = 72*jj + cc, cc<66 real)
// blocks [2176,2304): WTu[o][k]
__global__ void prologue_kernel(const float* __restrict__ E, __bf16* __restrict__ S,
                                const float* __restrict__ Wg, __bf16* __restrict__ WTg,
                                const float* __restrict__ Wu, __bf16* __restrict__ WTu) {
    const int bid = blockIdx.x;
    const int t = threadIdx.x;            // 256
    __shared__ float sm[4], ss[4];
    if (bid >= 2048) {
        const float* W = (bid < 2176) ? Wg : Wu;
        __bf16* WT = (bid < 2176) ? WTg : WTu;
        const int Nout = (bid < 2176) ? 128 : 64;
        const int id = (bid - ((bid < 2176) ? 2048 : 2176)) * 256 + t;  // 128*256
        const int o = id >> 8, k = id & 255;
        const int jj = (k >= 144) ? 2 : (k >= 72 ? 1 : 0);
        const int cc = k - 72 * jj;
        const bool ok = (o < Nout) && (cc < 66) && (k < 216);
        WT[id] = ok ? (__bf16)W[(size_t)(66 * jj + cc) * Nout + o] : (__bf16)0.f;
        return;
    }
    const int n = bid;
    const int l = t & 63, w = t >> 6;
    float en[10];
#pragma unroll
    for (int i = 0; i < 10; ++i) en[i] = E[n * 10 + i];
    float vals[8];
    float mx = 0.f;
#pragma unroll
    for (int q = 0; q < 8; ++q) {
        const int m = q * 256 + t;
        const float* em = E + (size_t)m * 10;
        float d = 0.f;
#pragma unroll
        for (int i = 0; i < 10; ++i) d += en[i] * em[i];
        d = fmaxf(d, 0.f);
        vals[q] = d;
        mx = fmaxf(mx, d);
    }
#pragma unroll
    for (int off = 32; off; off >>= 1) mx = fmaxf(mx, __shfl_xor(mx, off));
    if (l == 0) sm[w] = mx;
    __syncthreads();
    mx = fmaxf(fmaxf(sm[0], sm[1]), fmaxf(sm[2], sm[3]));
    float sum = 0.f;
#pragma unroll
    for (int q = 0; q < 8; ++q) { vals[q] = __expf(vals[q] - mx); sum += vals[q]; }
#pragma unroll
    for (int off = 32; off; off >>= 1) sum += __shfl_xor(sum, off);
    if (l == 0) ss[w] = sum;
    __syncthreads();
    sum = ss[0] + ss[1] + ss[2] + ss[3];
    const float inv = 1.f / sum;
#pragma unroll
    for (int q = 0; q < 8; ++q) S[(size_t)n * 2048 + q * 256 + t] = (__bf16)(vals[q] * inv);
}

// ------- build T0 (T-layout [f=b*66+c][n]) + G section 0 (k in [0,72)) -------
__global__ __launch_bounds__(256, 2)
void build_t2(const float* __restrict__ x, const float* __restrict__ st,
              const __bf16* __restrict__ zr, __bf16* __restrict__ T,
              __bf16* __restrict__ G) {
    __shared__ float Ls[66 * 129];       // 34 KB
    const int b  = blockIdx.x >> 4;
    const int n0 = (blockIdx.x & 15) << 7;
    const int t = threadIdx.x;
    const size_t mb = (size_t)b * 2048 + n0;
    if (t < 128) {
        const float2 v = *(const float2*)&x[(mb + t) * 2];
        Ls[t] = v.x;
        Ls[129 + t] = v.y;
    }
#pragma unroll
    for (int r = 0; r < 8; ++r) {        // 128 rows x 16 col-quads
        const int task = r * 256 + t;
        const int q = task & 15, n = task >> 4;
        f32x4 v = *(const f32x4*)&st[(mb + n) * 64 + q * 4];
        if (zr) {
            const bf16x4 z = *(const bf16x4*)&zr[(mb + n) * 128 + q * 4];
#pragma unroll
            for (int j = 0; j < 4; ++j) v[j] *= (float)z[j];
        }
        const int base = (2 + q * 4) * 129 + n;
#pragma unroll
        for (int j = 0; j < 4; ++j) Ls[base + j * 129] = v[j];
    }
    __syncthreads();
    // T-layout store: coalesced columns
#pragma unroll
    for (int r = 0; r < 5; ++r) {        // 66 c x 16 segs = 1056 tasks
        const int task = r * 256 + t;
        if (task < 1056) {
            const int c = task >> 4, seg = task & 15;
            const float* src = &Ls[c * 129 + seg * 8];
            bf16x8 o;
#pragma unroll
            for (int j = 0; j < 8; ++j) o[j] = (__bf16)src[j];
            *(bf16x8*)&T[(size_t)(b * 66 + c) * 2048 + n0 + seg * 8] = o;
        }
    }
    // G section 0: row (b, n0+n), k = cc in [0,66), octets 0..8 (cc>=66 -> 0)
    {
        const int n = t & 127, half = t >> 7;
        const size_t grow = ((size_t)(b * 2048 + n0 + n)) * 256;
        for (int oct = half * 5; oct < (half ? 9 : 5); ++oct) {
            bf16x8 o8;
#pragma unroll
            for (int j = 0; j < 8; ++j) {
                const int cc = oct * 8 + j;
                o8[j] = (cc < 66) ? (__bf16)Ls[cc * 129 + n] : (__bf16)0.f;
            }
            *(bf16x8*)&G[grow + oct * 8] = o8;
        }
    }
}

// ---------------- pipelined GEMM: out[M][C] = A[M][K] @ Bt[C][K]^T ----------------
// 256 thr = 4 waves (2m x 2c), tile 128m x 64c, wave-tile 64x32 (4x2 frags), BK=64.
// Double-buffered LDS (48 KB -> 3 blocks/CU); per iter: stage next buf ->
// s_waitcnt vmcnt(6) (own cur-buf loads done; prefetch stays in flight) ->
// raw s_barrier -> compute -> raw s_barrier (frees buf). XOR-granule swizzle:
// conflict-free ds_read_b128. swz=1: mt = id&15, ct = id>>4 (XCD-pins A strips).
// epi: 0 outT[c][m]=bf16(acc), + G sec (gsec=72)
//      1 G sec only (gsec=144), val = 2*acc - subT[c][m]
//      2 zrO[m*128+c] = bf16(sigmoid(acc+bias[c]))
//      3 (c<64) outF[m*64+c] = r*state+(1-r)*tanh(acc+bias[c]), r=zrI[m*128+64+c]
__global__ __launch_bounds__(256, 3)
void gemm_pipe(const __bf16* __restrict__ A, int lda,
               const __bf16* __restrict__ Bt, int ldb,
               int K, int epi, int swz,
               __bf16* __restrict__ outT, const __bf16* __restrict__ subT,
               float* __restrict__ outF, const float* __restrict__ bias,
               __bf16* __restrict__ zrO, const __bf16* __restrict__ zrI,
               const float* __restrict__ state,
               __bf16* __restrict__ Gout, int gsec) {
    __shared__ __align__(16) __bf16 As[2][128 * 64];   // 32 KB
    __shared__ __align__(16) __bf16 Bs[2][64 * 64];    // 16 KB
    int mt, ct;
    if (swz) { mt = blockIdx.x & 15; ct = blockIdx.x >> 4; }
    else     { mt = blockIdx.x;      ct = blockIdx.y; }
    const int m0 = mt * 128, c0 = ct * 64;
    const int t = threadIdx.x;
    const int l = t & 63, w = t >> 6;
    const int wr = w >> 1, wc = w & 1;
    const int lm = l & 15, kq = l >> 4, lm7 = lm & 7;
    const int sr = l >> 3;               // row-within-chunk
    const int gsw = (l & 7) ^ sr;        // swizzled source granule

    f32x4 acc[4][2];
#pragma unroll
    for (int i = 0; i < 4; ++i)
#pragma unroll
        for (int j = 0; j < 2; ++j) acc[i][j] = (f32x4)0.f;

    const __bf16* Asrc = A  + (size_t)(m0 + w * 8 + sr) * lda + gsw * 8;
    const __bf16* Bsrc = Bt + (size_t)(c0 + w * 8 + sr) * ldb + gsw * 8;
    const int dstA = w * 512 + l * 8;

    auto stage = [&](int buf, int k0) {
#pragma unroll
        for (int q = 0; q < 4; ++q)
            __builtin_amdgcn_global_load_lds(GLB(Asrc + (size_t)q * 32 * lda + k0),
                                             LDS(&As[buf][q * 2048 + dstA]), 16, 0, 0);
#pragma unroll
        for (int q = 0; q < 2; ++q)
            __builtin_amdgcn_global_load_lds(GLB(Bsrc + (size_t)q * 32 * ldb + k0),
                                             LDS(&Bs[buf][q * 2048 + dstA]), 16, 0, 0);
    };
    auto compute = [&](int buf) {
        const __bf16* Ab = &As[buf][0];
        const __bf16* Bb = &Bs[buf][0];
#pragma unroll
        for (int ks = 0; ks < 2; ++ks) {
            const int ga = (((ks << 2) | kq) ^ lm7) << 3;
            bf16x8 af[4], bfr[2];
#pragma unroll
            for (int i = 0; i < 4; ++i)
                af[i] = *(const bf16x8*)&Ab[(wr * 64 + i * 16 + lm) * 64 + ga];
#pragma unroll
            for (int j = 0; j < 2; ++j)
                bfr[j] = *(const bf16x8*)&Bb[(wc * 32 + j * 16 + lm) * 64 + ga];
#pragma unroll
            for (int i = 0; i < 4; ++i)
#pragma unroll
                for (int j = 0; j < 2; ++j)
                    acc[i][j] = __builtin_amdgcn_mfma_f32_16x16x32_bf16(af[i], bfr[j], acc[i][j], 0, 0, 0);
        }
    };

    stage(0, 0);
    const int iters = K >> 6;            // even (32 big / 4 W)
    for (int i = 0; i + 2 <= iters; i += 2) {
        stage(1, (i + 1) << 6);
        __builtin_amdgcn_sched_barrier(0);
        __builtin_amdgcn_s_waitcnt(0x0F76);      // vmcnt(6): own buf0 loads done
        __builtin_amdgcn_s_barrier();
        __builtin_amdgcn_sched_barrier(0);
        compute(0);
        __builtin_amdgcn_sched_barrier(0);
        __builtin_amdgcn_s_barrier();            // buf0 free for restage
        __builtin_amdgcn_sched_barrier(0);
        if (i + 2 < iters) {
            stage(0, (i + 2) << 6);
            __builtin_amdgcn_sched_barrier(0);
            __builtin_amdgcn_s_waitcnt(0x0F76);  // vmcnt(6): own buf1 loads done
        } else {
            __builtin_amdgcn_s_waitcnt(0x0F70);  // vmcnt(0)
        }
        __builtin_amdgcn_s_barrier();
        __builtin_amdgcn_sched_barrier(0);
        compute(1);
        __builtin_amdgcn_sched_barrier(0);
        if (i + 4 <= iters) {
            __builtin_amdgcn_s_barrier();        // buf1 free for restage
            __builtin_amdgcn_sched_barrier(0);
        }
    }

    // epilogue: C row = m (quad*4+reg), col = lane&15  [verified m89 layout]
    const int rb0 = m0 + wr * 64 + kq * 4;
    const int cb0 = c0 + wc * 32 + lm;
#pragma unroll
    for (int i = 0; i < 4; ++i) {
        const int rbase = rb0 + i * 16;
#pragma unroll
        for (int j = 0; j < 2; ++j) {
            const int c = cb0 + j * 16;
            f32x4 v = acc[i][j];
            if (epi <= 1) {
                bf16x4 pk;
                if (epi == 0) {
#pragma unroll
                    for (int r = 0; r < 4; ++r) pk[r] = (__bf16)v[r];
                    *(bf16x4*)&outT[(size_t)c * 2048 + rbase] = pk;
                } else {
                    bf16x4 s = *(const bf16x4*)&subT[(size_t)c * 2048 + rbase];
#pragma unroll
                    for (int r = 0; r < 4; ++r) pk[r] = (__bf16)(2.f * v[r] - (float)s[r]);
                }
                // G scatter: row (b, n=rbase+r), k = gsec + cc, b = c/66
                const int b = c / 66, cc = c - b * 66;
                const size_t gb = ((size_t)(b * 2048 + rbase)) * 256 + gsec + cc;
#pragma unroll
                for (int r = 0; r < 4; ++r) Gout[gb + (size_t)r * 256] = pk[r];
            } else if (epi == 2) {
                const float bb = bias[c];
#pragma unroll
                for (int r = 0; r < 4; ++r) {
                    float xx = fminf(fmaxf(v[r] + bb, -30.f), 30.f);
                    zrO[(size_t)(rbase + r) * 128 + c] = (__bf16)(1.f / (1.f + __expf(-xx)));
                }
            } else {
                if (c < 64) {
                    const float bb = bias[c];
#pragma unroll
                    for (int r = 0; r < 4; ++r) {
                        const int m = rbase + r;
                        float xx = fminf(fmaxf(v[r] + bb, -15.f), 15.f);
                        float e = __expf(2.f * xx);
                        float hc = (e - 1.f) / (e + 1.f);
                        float rr = (float)zrI[(size_t)m * 128 + 64 + c];
                        float s = state[(size_t)m * 64 + c];
                        outF[(size_t)m * 64 + c] = rr * s + (1.f - rr) * hc;
                    }
                }
            }
        }
    }
}

extern "C" void kernel_launch(void* const* d_in, const int* in_sizes, int n_in,
                              void* d_out, int out_size, void* d_ws, size_t ws_size,
                              hipStream_t stream) {
    (void)in_sizes; (void)n_in; (void)out_size; (void)ws_size;
    const float* x  = (const float*)d_in[0];
    const float* st = (const float*)d_in[1];
    const float* E  = (const float*)d_in[2];
    const float* Wg = (const float*)d_in[3];
    const float* bg = (const float*)d_in[4];
    const float* Wu = (const float*)d_in[5];
    const float* bu = (const float*)d_in[6];
    float* out = (float*)d_out;

    char* p = (char*)d_ws;
    __bf16* S   = (__bf16*)p; p += (size_t)2048 * 2048 * 2;   // 8.4 MB
    __bf16* T0  = (__bf16*)p; p += (size_t)2112 * 2048 * 2;   // 8.65 MB
    __bf16* T1  = (__bf16*)p; p += (size_t)2112 * 2048 * 2;
    __bf16* G   = (__bf16*)p; p += (size_t)65536 * 256 * 2;   // 33.6 MB
    __bf16* ZR  = (__bf16*)p; p += (size_t)65536 * 128 * 2;   // 16.8 MB
    __bf16* WTg = (__bf16*)p; p += 128 * 256 * 2;
    __bf16* WTu = (__bf16*)p; p += 128 * 256 * 2;             // ~76 MB

    prologue_kernel<<<2304, 256, 0, stream>>>(E, S, Wg, WTg, Wu, WTu);

    // gate phase
    build_t2<<<512, 256, 0, stream>>>(x, st, nullptr, T0, G);
    gemm_pipe<<<528, 256, 0, stream>>>(S, 2048, T0, 2048, 2048, 0, 1, T1, nullptr, nullptr, nullptr, nullptr, nullptr, nullptr, G, 72);
    gemm_pipe<<<528, 256, 0, stream>>>(S, 2048, T1, 2048, 2048, 1, 1, nullptr, T0, nullptr, nullptr, nullptr, nullptr, nullptr, G, 144);
    gemm_pipe<<<dim3(512, 2), 256, 0, stream>>>(G, 256, WTg, 256, 256, 2, 0, nullptr, nullptr, nullptr, bg, ZR, nullptr, nullptr, nullptr, 0);

    // update phase
    build_t2<<<512, 256, 0, stream>>>(x, st, ZR, T0, G);
    gemm_pipe<<<528, 256, 0, stream>>>(S, 2048, T0, 2048, 2048, 0, 1, T1, nullptr, nullptr, nullptr, nullptr, nullptr, nullptr, G, 72);
    gemm_pipe<<<528, 256, 0, stream>>>(S, 2048, T1, 2048, 2048, 1, 1, nullptr, T0, nullptr, nullptr, nullptr, nullptr, nullptr, G, 144);
    gemm_pipe<<<dim3(512, 1), 256, 0, stream>>>(G, 256, WTu, 256, 256, 3, 0, nullptr, nullptr, out, bu, nullptr, ZR, st, nullptr, 0);
}